// Round 9
// baseline (378.935 us; speedup 1.0000x reference)
//
#include <hip/hip_runtime.h>

typedef unsigned long long u64;
typedef int i32x4 __attribute__((ext_vector_type(4)));
typedef int i32x16 __attribute__((ext_vector_type(16)));

#define N_SP 3136          // 56*56
#define C_IN 256
#define C_OUT 256
#define BATCH 32
#define NBLK 896           // 32 b x 28 row-pairs
// xsignT: [b][hp 0..57][wp stride 64 (0..57 used)][ci 0..255] int8, zero borders
#define XROW 64
#define XPLANE (58 * XROW * 256)          // per-image bytes = 950272
#define XSIZE ((size_t)BATCH * XPLANE)    // 30,408,704 B

// ---------------------------------------------------------------- weight prep
// One block per output channel o (256 threads = one per input channel).
// wc = w - mean_over_Cin (fp64); A_pack = fragment-ordered sign bytes;
// alpha[o] = mean |clamp(wc,±1)| (fp64).
__global__ __launch_bounds__(256) void prep_weights(const float* __restrict__ w,
                                                    char* __restrict__ A_pack,
                                                    double* __restrict__ alpha) {
    const int o = blockIdx.x;
    const int i = threadIdx.x;           // input channel
    const int lane = i & 63, wvid = i >> 6;
    __shared__ double part[4][9];
    __shared__ double part2[4];

    float wv[9];
    const float* wp = w + ((size_t)o * C_IN + i) * 9;
#pragma unroll
    for (int t = 0; t < 9; ++t) wv[t] = wp[t];

#pragma unroll
    for (int t = 0; t < 9; ++t) {
        double v = (double)wv[t];
#pragma unroll
        for (int off = 32; off > 0; off >>= 1) v += __shfl_down(v, off);
        if (lane == 0) part[wvid][t] = v;
    }
    __syncthreads();

    double asum = 0.0;
#pragma unroll
    for (int t = 0; t < 9; ++t) {
        double mean = (part[0][t] + part[1][t] + part[2][t] + part[3][t]) * (1.0 / 256.0);
        double wc = (double)wv[t] - mean;
        // fragment-order scatter: idx16 = ((t*8 + ci/32)*8 + o/32)*64 + ((ci>>4)&1)*32 + (o&31)
        int idx16 = ((t * 8 + (i >> 5)) * 8 + (o >> 5)) * 64 + (((i >> 4) & 1) << 5) + (o & 31);
        A_pack[(size_t)idx16 * 16 + (i & 15)] = (char)(wc > 0.0 ? 1 : -1);
        double aw = fabs(wc);
        if (aw > 1.0) aw = 1.0;
        asum += aw;
    }
#pragma unroll
    for (int off = 32; off > 0; off >>= 1) asum += __shfl_down(asum, off);
    if (lane == 0) part2[wvid] = asum;
    __syncthreads();
    if (i == 0)
        alpha[o] = (part2[0] + part2[1] + part2[2] + part2[3]) * (1.0 / 2304.0);
}

// ---------------------------------------------------------------- zero borders
// Interior (hp 1..56, wp 1..56) is fully overwritten by sign_transpose; only
// border strips need zeroing.
__global__ __launch_bounds__(256) void zero_borders(char* __restrict__ xsT) {
    const int tid = blockIdx.x * 256 + threadIdx.x;   // 0 .. 294911
    const int b = tid / 9216;
    const int r = tid - b * 9216;
    int hp, wp, c16;
    if (r < 2048) {                       // full rows 0 and 57
        hp = (r >> 10) * 57;
        wp = (r >> 4) & 63;
        c16 = (r & 15) << 4;
    } else {                              // cols 0, 57..63 of rows 1..56
        int r2 = r - 2048;
        hp = 1 + (r2 >> 7);
        int q = r2 & 127;
        int wi = q >> 4;
        wp = (wi == 0) ? 0 : 56 + wi;
        c16 = (q & 15) << 4;
    }
    *(i32x4*)(xsT + (((size_t)(b * 58 + hp) << 6) + wp) * 256 + c16) = (i32x4){0, 0, 0, 0};
}

// ---------------------------------------------------------------- sign transpose
// grid (49, 32): sp-tile of 64, image b. Reads x[b][ci][sp] coalesced,
// packs sign bytes, LDS-transposes to channel-last, 16B/lane stores.
__global__ __launch_bounds__(256) void sign_transpose(const float* __restrict__ x,
                                                      char* __restrict__ xsT) {
    const int sp0 = blockIdx.x * 64;
    const int b = blockIdx.y;
    const int lane = threadIdx.x & 63;     // sp within tile
    const int wv = threadIdx.x >> 6;       // ci block of 64
    __shared__ char tile[64 * 272];        // [sp][ci], +16 pad

    const float* xp = x + ((size_t)(b * 256 + (wv << 6))) * N_SP + sp0 + lane;
#pragma unroll
    for (int q = 0; q < 4; ++q) {          // 4 × 16 ci -> 4 × b128 LDS writes
        unsigned d[4];
#pragma unroll
        for (int dd = 0; dd < 4; ++dd) {
            unsigned v = 0;
#pragma unroll
            for (int kk = 0; kk < 4; ++kk) {
                int ci_l = (q << 4) + (dd << 2) + kk;
                float xv = xp[(size_t)ci_l * N_SP];
                v |= (unsigned)(xv > 0.0f ? 0x01u : 0xFFu) << (8 * kk);
            }
            d[dd] = v;
        }
        *(i32x4*)(tile + lane * 272 + (wv << 6) + (q << 4)) =
            (i32x4){(int)d[0], (int)d[1], (int)d[2], (int)d[3]};
    }
    __syncthreads();

    const int t = threadIdx.x;
#pragma unroll
    for (int j = 0; j < 4; ++j) {
        int sp_loc = (j << 4) + (t >> 4);
        int ci0 = (t & 15) << 4;
        i32x4 v = *(const i32x4*)(tile + sp_loc * 272 + ci0);
        int spg = sp0 + sp_loc;
        int h = spg / 56, w = spg - h * 56;
        size_t dst = (((size_t)(b * 58 + h + 1) << 6) + (w + 1)) * 256 + ci0;
        *(i32x4*)(xsT + dst) = v;
    }
}

// ---------------------------------------------------------------- MFMA conv
// grid 896 = 32b * 28 row-pairs, block 512 = 8 waves. Block tile: 256 co x
// 2 rows x 64 n. Wave wv = co-block 32wv..32wv+31: 4 accs (64 VGPRs) — R8's
// 8-acc wave (128 VGPRs) spilled accumulators to scratch (+250 MB HBM).
// 8 waves/block, 2 blocks/CU -> 4 waves/SIMD TLP for latency hiding.
// Per-block channel stats partials computed in-epilogue (no atomics) — kills
// the 103 MB stats_reduce re-read.
// Fragment layouts (verified R6-R8, absmax 0): A/B m|n=lane&31, k=(lane>>5)*16+j;
// C/D col=lane&31, row=(reg&3)+8*(reg>>2)+4*(lane>>5).
__global__ __launch_bounds__(512) void conv_mfma(const char* __restrict__ xsT,
                                                 const char* __restrict__ A_pack,
                                                 float* __restrict__ out,
                                                 int2* __restrict__ partials) {
    const int tid = threadIdx.x;
    const int lane = tid & 63;
    const int wv = tid >> 6;              // co-block 0..7
    const int l31 = lane & 31, l5 = lane >> 5;
    const int blk = blockIdx.x;
    const int b = blk / 28;
    const int h0 = (blk - b * 28) * 2;

    __shared__ char slab[4 * 66 * 272];   // [dh 0..3][wp 0..65][ci], ci padded to 272

    // stage 4 source rows (padded h0..h0+3) of 64 wp x 256 ci
    {
        const char* src = xsT + ((size_t)(b * 58 + h0) << 6) * 256;
        for (int c = tid; c < 4 * 64 * 16; c += 512) {       // 16B chunks
            int dh = c >> 10, rem = c & 1023, wp = rem >> 4, c16 = (rem & 15) << 4;
            *(i32x4*)(slab + (dh * 66 + wp) * 272 + c16) =
                *(const i32x4*)(src + (size_t)dh * (XROW * 256) + wp * 256 + c16);
        }
        if (tid < 128) {                                     // zero cols 64,65
            int dh = tid >> 5, wp = 64 + ((tid >> 4) & 1), c16 = (tid & 15) << 4;
            *(i32x4*)(slab + (dh * 66 + wp) * 272 + c16) = (i32x4){0, 0, 0, 0};
        }
    }
    __syncthreads();

    i32x16 acc[2][2] = {};   // [nh][row]

#pragma unroll
    for (int tap = 0; tap < 9; ++tap) {
        const int dh = tap / 3, dw = tap % 3;
#pragma unroll
        for (int cib = 0; cib < 8; ++cib) {
            i32x4 af = *(const i32x4*)(A_pack +
                ((size_t)(((tap * 8 + cib) * 8 + wv) * 64 + lane) << 4));
            i32x4 bf[2][2];
#pragma unroll
            for (int nh = 0; nh < 2; ++nh)
#pragma unroll
                for (int row = 0; row < 2; ++row)
                    bf[nh][row] = *(const i32x4*)(slab +
                        ((dh + row) * 66 + (nh * 32 + l31) + dw) * 272 + l5 * 16 + cib * 32);
#pragma unroll
            for (int nh = 0; nh < 2; ++nh)
#pragma unroll
                for (int row = 0; row < 2; ++row)
                    acc[nh][row] = __builtin_amdgcn_mfma_i32_32x32x32_i8(
                        af, bf[nh][row], acc[nh][row], 0, 0, 0);
        }
    }

    // ---- stores: S exact integer as float ----
    float* ob = out + ((size_t)(b * 256 + wv * 32)) * N_SP + h0 * 56;
#pragma unroll
    for (int nh = 0; nh < 2; ++nh) {
        const int w = nh * 32 + l31;
        if (w < 56) {
#pragma unroll
            for (int row = 0; row < 2; ++row)
#pragma unroll
                for (int reg = 0; reg < 16; ++reg) {
                    int corow = (reg & 3) + 8 * (reg >> 2) + 4 * l5;
                    ob[(size_t)corow * N_SP + row * 56 + w] = (float)acc[nh][row][reg];
                }
        }
    }

    // ---- per-block channel stats partials (no atomics) ----
    __syncthreads();                       // all waves done reading slab
    int* sp_s = (int*)slab;                // [256]
    int* sp_q = (int*)slab + 256;          // [256]
#pragma unroll
    for (int reg = 0; reg < 16; ++reg) {
        int v00 = acc[0][0][reg], v01 = acc[0][1][reg];
        int v10 = (l31 < 24) ? acc[1][0][reg] : 0;
        int v11 = (l31 < 24) ? acc[1][1][reg] : 0;
        int s = v00 + v01 + v10 + v11;
        unsigned q = (unsigned)(v00 * v00) + (unsigned)(v01 * v01)
                   + (unsigned)(v10 * v10) + (unsigned)(v11 * v11);
#pragma unroll
        for (int off = 16; off > 0; off >>= 1) {   // reduce within 32-lane half
            s += __shfl_xor(s, off);
            q += (unsigned)__shfl_xor((int)q, off);
        }
        if (l31 == 0) {
            int corow = (reg & 3) + 8 * (reg >> 2) + 4 * l5;
            sp_s[wv * 32 + corow] = s;
            sp_q[wv * 32 + corow] = (int)q;       // q <= ~6.8e8, fits int
        }
    }
    __syncthreads();
    if (tid < 256)
        partials[(size_t)tid * NBLK + blk] = make_int2(sp_s[tid], sp_q[tid]);
}

// ---------------------------------------------------------------- stats+consts
// grid 256 = one block per channel: sum 896 block-partials (coalesced row
// read, 7 KB), then thread 0 computes the affine threshold constants.
__global__ __launch_bounds__(256) void stats_consts(const int2* __restrict__ partials,
                                                    const double* __restrict__ alpha,
                                                    const float* __restrict__ gamma,
                                                    const float* __restrict__ beta,
                                                    double* __restrict__ AB) {
    const int c = blockIdx.x;
    const int t = threadIdx.x;
    long long s1 = 0, s2 = 0;
    for (int blk = t; blk < NBLK; blk += 256) {
        int2 v = partials[(size_t)c * NBLK + blk];
        s1 += v.x;
        s2 += (long long)v.y;
    }
#pragma unroll
    for (int off = 32; off > 0; off >>= 1) {
        s1 += __shfl_down(s1, off);
        s2 += __shfl_down(s2, off);
    }
    __shared__ long long p1[4], p2[4];
    if ((t & 63) == 0) { p1[t >> 6] = s1; p2[t >> 6] = s2; }
    __syncthreads();
    if (t == 0) {
        double S1 = (double)(p1[0] + p1[1] + p1[2] + p1[3]);
        double S2 = (double)(p2[0] + p2[1] + p2[2] + p2[3]);
        const double N = (double)(BATCH * N_SP);
        double mu = S1 / N;
        double var = S2 / N - mu * mu;
        double a = alpha[c];
        double vy = a * a * var;
        double scale = (double)gamma[c] / sqrt(vy + 1e-5);
        double A = a * scale;
        double B = (double)beta[c] - A * mu;
        AB[c] = A;
        AB[C_OUT + c] = B;
    }
}

// ---------------------------------------------------------------- finalize
// In-place: d_out holds exact-integer S as float; out = (A*S+B > 0) ? 1 : 0.
__global__ __launch_bounds__(256) void finalize(float* __restrict__ out,
                                                const double* __restrict__ AB) {
    const unsigned i4 = blockIdx.x * 256 + threadIdx.x;   // 0 .. 6422527
    const unsigned e = i4 << 2;                            // element base
    const int c = (int)((e / N_SP) & (C_OUT - 1));         // 3136 | 4 -> c uniform in float4
    const double A = AB[c];
    const double B = AB[C_OUT + c];
    float4 v = ((float4*)out)[i4];
    v.x = (A * (double)v.x + B) > 0.0 ? 1.0f : 0.0f;
    v.y = (A * (double)v.y + B) > 0.0 ? 1.0f : 0.0f;
    v.z = (A * (double)v.z + B) > 0.0 ? 1.0f : 0.0f;
    v.w = (A * (double)v.w + B) > 0.0 ? 1.0f : 0.0f;
    ((float4*)out)[i4] = v;
}

// ---------------------------------------------------------------- launch
extern "C" void kernel_launch(void* const* d_in, const int* in_sizes, int n_in,
                              void* d_out, int out_size, void* d_ws, size_t ws_size,
                              hipStream_t stream) {
    const float* x      = (const float*)d_in[0];
    const float* weight = (const float*)d_in[1];
    const float* bias   = (const float*)d_in[2];   (void)bias;  // cancels in BN
    const float* gamma  = (const float*)d_in[3];
    const float* beta   = (const float*)d_in[4];
    float* out = (float*)d_out;

    char* ws = (char*)d_ws;
    double* alpha = (double*)(ws + 4096);       // [256]
    double* AB    = (double*)(ws + 8192);       // [512]
    char*   A_pack = (char*)(ws + 16384);       // 589,824 B fragment-ordered signs
    char*   xsT   = (char*)(ws + (1 << 20));    // 30,408,704 B padded channel-last signs
    int2*   partials = (int2*)(ws + (1 << 20) + 31 * (1 << 20));  // 256*896*8 = 1.8 MB

    prep_weights<<<C_OUT, 256, 0, stream>>>(weight, A_pack, alpha);
    zero_borders<<<1152, 256, 0, stream>>>(xsT);
    sign_transpose<<<dim3(49, BATCH), 256, 0, stream>>>(x, xsT);
    conv_mfma<<<NBLK, 512, 0, stream>>>(xsT, A_pack, out, partials);
    stats_consts<<<C_OUT, 256, 0, stream>>>(partials, alpha, gamma, beta, AB);
    finalize<<<(out_size / 4) / 256, 256, 0, stream>>>(out, AB);
}

// Round 10
// 348.527 us; speedup vs baseline: 1.0872x; 1.0872x over previous
//
#include <hip/hip_runtime.h>

typedef unsigned long long u64;
typedef int i32x4 __attribute__((ext_vector_type(4)));
typedef int i32x16 __attribute__((ext_vector_type(16)));

#define N_SP 3136          // 56*56
#define C_IN 256
#define C_OUT 256
#define BATCH 32
#define NBLK 896           // 32 b x 28 row-pairs (x-dim of conv grid)
// xsignT: [b][hp 0..57][wp stride 64 (0..57 used)][ci 0..255] int8, zero borders
#define XROW 64
#define XPLANE (58 * XROW * 256)          // per-image bytes = 950272
#define XSIZE ((size_t)BATCH * XPLANE)    // 30,408,704 B

// ---------------------------------------------------------------- weight prep
// One block per output channel o (256 threads = one per input channel).
// wc = w - mean_over_Cin (fp64); A_pack = fragment-ordered sign bytes;
// alpha[o] = mean |clamp(wc,±1)| (fp64).
__global__ __launch_bounds__(256) void prep_weights(const float* __restrict__ w,
                                                    char* __restrict__ A_pack,
                                                    double* __restrict__ alpha) {
    const int o = blockIdx.x;
    const int i = threadIdx.x;           // input channel
    const int lane = i & 63, wvid = i >> 6;
    __shared__ double part[4][9];
    __shared__ double part2[4];

    float wv[9];
    const float* wp = w + ((size_t)o * C_IN + i) * 9;
#pragma unroll
    for (int t = 0; t < 9; ++t) wv[t] = wp[t];

#pragma unroll
    for (int t = 0; t < 9; ++t) {
        double v = (double)wv[t];
#pragma unroll
        for (int off = 32; off > 0; off >>= 1) v += __shfl_down(v, off);
        if (lane == 0) part[wvid][t] = v;
    }
    __syncthreads();

    double asum = 0.0;
#pragma unroll
    for (int t = 0; t < 9; ++t) {
        double mean = (part[0][t] + part[1][t] + part[2][t] + part[3][t]) * (1.0 / 256.0);
        double wc = (double)wv[t] - mean;
        // fragment-order scatter: idx16 = ((t*8 + ci/32)*8 + o/32)*64 + ((ci>>4)&1)*32 + (o&31)
        int idx16 = ((t * 8 + (i >> 5)) * 8 + (o >> 5)) * 64 + (((i >> 4) & 1) << 5) + (o & 31);
        A_pack[(size_t)idx16 * 16 + (i & 15)] = (char)(wc > 0.0 ? 1 : -1);
        double aw = fabs(wc);
        if (aw > 1.0) aw = 1.0;
        asum += aw;
    }
#pragma unroll
    for (int off = 32; off > 0; off >>= 1) asum += __shfl_down(asum, off);
    if (lane == 0) part2[wvid] = asum;
    __syncthreads();
    if (i == 0)
        alpha[o] = (part2[0] + part2[1] + part2[2] + part2[3]) * (1.0 / 2304.0);
}

// ---------------------------------------------------------------- zero borders
// Interior (hp 1..56, wp 1..56) is fully overwritten by sign_transpose; only
// border strips need zeroing.
__global__ __launch_bounds__(256) void zero_borders(char* __restrict__ xsT) {
    const int tid = blockIdx.x * 256 + threadIdx.x;   // 0 .. 294911
    const int b = tid / 9216;
    const int r = tid - b * 9216;
    int hp, wp, c16;
    if (r < 2048) {                       // full rows 0 and 57
        hp = (r >> 10) * 57;
        wp = (r >> 4) & 63;
        c16 = (r & 15) << 4;
    } else {                              // cols 0, 57..63 of rows 1..56
        int r2 = r - 2048;
        hp = 1 + (r2 >> 7);
        int q = r2 & 127;
        int wi = q >> 4;
        wp = (wi == 0) ? 0 : 56 + wi;
        c16 = (q & 15) << 4;
    }
    *(i32x4*)(xsT + (((size_t)(b * 58 + hp) << 6) + wp) * 256 + c16) = (i32x4){0, 0, 0, 0};
}

// ---------------------------------------------------------------- sign transpose
// grid (49, 32): sp-tile of 64, image b. Reads x[b][ci][sp] coalesced,
// packs sign bytes, LDS-transposes to channel-last, 16B/lane stores.
__global__ __launch_bounds__(256) void sign_transpose(const float* __restrict__ x,
                                                      char* __restrict__ xsT) {
    const int sp0 = blockIdx.x * 64;
    const int b = blockIdx.y;
    const int lane = threadIdx.x & 63;     // sp within tile
    const int wv = threadIdx.x >> 6;       // ci block of 64
    __shared__ char tile[64 * 272];        // [sp][ci], +16 pad

    const float* xp = x + ((size_t)(b * 256 + (wv << 6))) * N_SP + sp0 + lane;
#pragma unroll
    for (int q = 0; q < 4; ++q) {          // 4 × 16 ci -> 4 × b128 LDS writes
        unsigned d[4];
#pragma unroll
        for (int dd = 0; dd < 4; ++dd) {
            unsigned v = 0;
#pragma unroll
            for (int kk = 0; kk < 4; ++kk) {
                int ci_l = (q << 4) + (dd << 2) + kk;
                float xv = xp[(size_t)ci_l * N_SP];
                v |= (unsigned)(xv > 0.0f ? 0x01u : 0xFFu) << (8 * kk);
            }
            d[dd] = v;
        }
        *(i32x4*)(tile + lane * 272 + (wv << 6) + (q << 4)) =
            (i32x4){(int)d[0], (int)d[1], (int)d[2], (int)d[3]};
    }
    __syncthreads();

    const int t = threadIdx.x;
#pragma unroll
    for (int j = 0; j < 4; ++j) {
        int sp_loc = (j << 4) + (t >> 4);
        int ci0 = (t & 15) << 4;
        i32x4 v = *(const i32x4*)(tile + sp_loc * 272 + ci0);
        int spg = sp0 + sp_loc;
        int h = spg / 56, w = spg - h * 56;
        size_t dst = (((size_t)(b * 58 + h + 1) << 6) + (w + 1)) * 256 + ci0;
        *(i32x4*)(xsT + dst) = v;
    }
}

// ---------------------------------------------------------------- MFMA conv
// grid (896, 2), block 256 = 4 waves. Block tile: 128 co (co-tile y) x 2 rows
// x 64 n. Wave wv = co-block (y*4+wv)*32: acc[2][2] = 4 accs (64 VGPRs).
// __launch_bounds__(256, 2) -> 256-VGPR budget: R8/R9 pegged the default
// 128-VGPR target and spilled ACCUMULATORS to scratch (+230 MB HBM traffic,
// MfmaUtil 14-20%). 2 blocks/CU by LDS (72 KB each), 8 waves/CU.
// Per-block channel stats partials in-epilogue (no atomics).
// Fragment layouts (verified R6-R9, absmax 0): A/B m|n=lane&31, k=(lane>>5)*16+j;
// C/D col=lane&31, row=(reg&3)+8*(reg>>2)+4*(lane>>5).
__global__ __launch_bounds__(256, 2) void conv_mfma(const char* __restrict__ xsT,
                                                    const char* __restrict__ A_pack,
                                                    float* __restrict__ out,
                                                    int2* __restrict__ partials) {
    const int tid = threadIdx.x;
    const int lane = tid & 63;
    const int wv = tid >> 6;              // co-block within tile, 0..3
    const int l31 = lane & 31, l5 = lane >> 5;
    const int blk = blockIdx.x;
    const int y = blockIdx.y;             // co-tile (128 channels)
    const int b = blk / 28;
    const int h0 = (blk - b * 28) * 2;
    const int co5 = y * 4 + wv;           // 32-channel block index, 0..7

    __shared__ char slab[4 * 66 * 272];   // [dh 0..3][wp 0..65][ci], ci padded to 272

    // stage 4 source rows (padded h0..h0+3) of 64 wp x 256 ci
    {
        const char* src = xsT + ((size_t)(b * 58 + h0) << 6) * 256;
        for (int c = tid; c < 4 * 64 * 16; c += 256) {       // 16B chunks
            int dh = c >> 10, rem = c & 1023, wp = rem >> 4, c16 = (rem & 15) << 4;
            *(i32x4*)(slab + (dh * 66 + wp) * 272 + c16) =
                *(const i32x4*)(src + (size_t)dh * (XROW * 256) + wp * 256 + c16);
        }
        if (tid < 128) {                                     // zero cols 64,65
            int dh = tid >> 5, wp = 64 + ((tid >> 4) & 1), c16 = (tid & 15) << 4;
            *(i32x4*)(slab + (dh * 66 + wp) * 272 + c16) = (i32x4){0, 0, 0, 0};
        }
    }
    __syncthreads();

    i32x16 acc[2][2] = {};   // [nh][row]

#pragma unroll
    for (int tap = 0; tap < 9; ++tap) {
        const int dh = tap / 3, dw = tap % 3;
#pragma unroll
        for (int cib = 0; cib < 8; ++cib) {
            i32x4 af = *(const i32x4*)(A_pack +
                ((size_t)(((tap * 8 + cib) * 8 + co5) * 64 + lane) << 4));
            i32x4 bf[2][2];
#pragma unroll
            for (int nh = 0; nh < 2; ++nh)
#pragma unroll
                for (int row = 0; row < 2; ++row)
                    bf[nh][row] = *(const i32x4*)(slab +
                        ((dh + row) * 66 + (nh * 32 + l31) + dw) * 272 + l5 * 16 + cib * 32);
#pragma unroll
            for (int nh = 0; nh < 2; ++nh)
#pragma unroll
                for (int row = 0; row < 2; ++row)
                    acc[nh][row] = __builtin_amdgcn_mfma_i32_32x32x32_i8(
                        af, bf[nh][row], acc[nh][row], 0, 0, 0);
        }
    }

    // ---- stores: S exact integer as float ----
    float* ob = out + ((size_t)(b * 256 + co5 * 32)) * N_SP + h0 * 56;
#pragma unroll
    for (int nh = 0; nh < 2; ++nh) {
        const int w = nh * 32 + l31;
        if (w < 56) {
#pragma unroll
            for (int row = 0; row < 2; ++row)
#pragma unroll
                for (int reg = 0; reg < 16; ++reg) {
                    int corow = (reg & 3) + 8 * (reg >> 2) + 4 * l5;
                    ob[(size_t)corow * N_SP + row * 56 + w] = (float)acc[nh][row][reg];
                }
        }
    }

    // ---- per-block channel stats partials (no atomics) ----
    __syncthreads();                       // all waves done reading slab
    int* sp_s = (int*)slab;                // [128]
    int* sp_q = (int*)slab + 128;          // [128]
#pragma unroll
    for (int reg = 0; reg < 16; ++reg) {
        int v00 = acc[0][0][reg], v01 = acc[0][1][reg];
        int v10 = (l31 < 24) ? acc[1][0][reg] : 0;
        int v11 = (l31 < 24) ? acc[1][1][reg] : 0;
        int s = v00 + v01 + v10 + v11;
        unsigned q = (unsigned)(v00 * v00) + (unsigned)(v01 * v01)
                   + (unsigned)(v10 * v10) + (unsigned)(v11 * v11);
#pragma unroll
        for (int off = 16; off > 0; off >>= 1) {   // reduce within 32-lane half
            s += __shfl_xor(s, off);
            q += (unsigned)__shfl_xor((int)q, off);
        }
        if (l31 == 0) {
            int corow = (reg & 3) + 8 * (reg >> 2) + 4 * l5;
            sp_s[wv * 32 + corow] = s;
            sp_q[wv * 32 + corow] = (int)q;       // q <= ~6.8e8, fits int
        }
    }
    __syncthreads();
    if (tid < 128)
        partials[(size_t)(y * 128 + tid) * NBLK + blk] = make_int2(sp_s[tid], sp_q[tid]);
}

// ---------------------------------------------------------------- stats+consts
// grid 256 = one block per channel: sum 896 block-partials (coalesced row
// read, 7 KB), then thread 0 computes the affine threshold constants.
__global__ __launch_bounds__(256) void stats_consts(const int2* __restrict__ partials,
                                                    const double* __restrict__ alpha,
                                                    const float* __restrict__ gamma,
                                                    const float* __restrict__ beta,
                                                    double* __restrict__ AB) {
    const int c = blockIdx.x;
    const int t = threadIdx.x;
    long long s1 = 0, s2 = 0;
    for (int blk = t; blk < NBLK; blk += 256) {
        int2 v = partials[(size_t)c * NBLK + blk];
        s1 += v.x;
        s2 += (long long)v.y;
    }
#pragma unroll
    for (int off = 32; off > 0; off >>= 1) {
        s1 += __shfl_down(s1, off);
        s2 += __shfl_down(s2, off);
    }
    __shared__ long long p1[4], p2[4];
    if ((t & 63) == 0) { p1[t >> 6] = s1; p2[t >> 6] = s2; }
    __syncthreads();
    if (t == 0) {
        double S1 = (double)(p1[0] + p1[1] + p1[2] + p1[3]);
        double S2 = (double)(p2[0] + p2[1] + p2[2] + p2[3]);
        const double N = (double)(BATCH * N_SP);
        double mu = S1 / N;
        double var = S2 / N - mu * mu;
        double a = alpha[c];
        double vy = a * a * var;
        double scale = (double)gamma[c] / sqrt(vy + 1e-5);
        double A = a * scale;
        double B = (double)beta[c] - A * mu;
        AB[c] = A;
        AB[C_OUT + c] = B;
    }
}

// ---------------------------------------------------------------- finalize
// In-place: d_out holds exact-integer S as float; out = (A*S+B > 0) ? 1 : 0.
__global__ __launch_bounds__(256) void finalize(float* __restrict__ out,
                                                const double* __restrict__ AB) {
    const unsigned i4 = blockIdx.x * 256 + threadIdx.x;   // 0 .. 6422527
    const unsigned e = i4 << 2;                            // element base
    const int c = (int)((e / N_SP) & (C_OUT - 1));         // 3136 | 4 -> c uniform in float4
    const double A = AB[c];
    const double B = AB[C_OUT + c];
    float4 v = ((float4*)out)[i4];
    v.x = (A * (double)v.x + B) > 0.0 ? 1.0f : 0.0f;
    v.y = (A * (double)v.y + B) > 0.0 ? 1.0f : 0.0f;
    v.z = (A * (double)v.z + B) > 0.0 ? 1.0f : 0.0f;
    v.w = (A * (double)v.w + B) > 0.0 ? 1.0f : 0.0f;
    ((float4*)out)[i4] = v;
}

// ---------------------------------------------------------------- launch
extern "C" void kernel_launch(void* const* d_in, const int* in_sizes, int n_in,
                              void* d_out, int out_size, void* d_ws, size_t ws_size,
                              hipStream_t stream) {
    const float* x      = (const float*)d_in[0];
    const float* weight = (const float*)d_in[1];
    const float* bias   = (const float*)d_in[2];   (void)bias;  // cancels in BN
    const float* gamma  = (const float*)d_in[3];
    const float* beta   = (const float*)d_in[4];
    float* out = (float*)d_out;

    char* ws = (char*)d_ws;
    double* alpha = (double*)(ws + 4096);       // [256]
    double* AB    = (double*)(ws + 8192);       // [512]
    char*   A_pack = (char*)(ws + 16384);       // 589,824 B fragment-ordered signs
    char*   xsT   = (char*)(ws + (1 << 20));    // 30,408,704 B padded channel-last signs
    int2*   partials = (int2*)(ws + 32 * (1 << 20));  // 256*896*8 = 1.8 MB

    prep_weights<<<C_OUT, 256, 0, stream>>>(weight, A_pack, alpha);
    zero_borders<<<1152, 256, 0, stream>>>(xsT);
    sign_transpose<<<dim3(49, BATCH), 256, 0, stream>>>(x, xsT);
    conv_mfma<<<dim3(NBLK, 2), 256, 0, stream>>>(xsT, A_pack, out, partials);
    stats_consts<<<C_OUT, 256, 0, stream>>>(partials, alpha, gamma, beta, AB);
    finalize<<<(out_size / 4) / 256, 256, 0, stream>>>(out, AB);
}